// Round 9
// baseline (232.002 us; speedup 1.0000x reference)
//
#include <hip/hip_runtime.h>

// GlobalAttentionPooling: tensor_square_0e -> selu -> @W -> segment softmax -> weighted segment sum
// N nodes, 80 f32 ft (32 scalar + 16 x 3-vec), NG=1024 graphs (sorted batch_index), F=664.
//
// Math identities (validated rounds 1-7, absmax 3.9e-3):
//   selu const term cancels in softmax; scale si by log2e (sj raw) so pair products are
//   f*log2e -> exp2 directly. out_g = (sum nf*ex)/z_g.
//
// Round-9: round 8's design with the vector-part j-load index FIXED:
//   j-group for pair qq covers floats 32+6qq..+11 => float4 base 8 + 3*(qq>>1),
//   (round 8 used 8 + 3*qq -> read past the row => absmax 0.95).
// Design recap: the compiler refuses to keep an 80-float row live across the unrolled
// 344-pair triangle (r5/r6 VGPR=36, r7 VGPR=72 — always sinks/reloads operands from
// cache scalar-wise). So we DESIGN the reload: 8-channel i-blocks held live, j-pairs
// streamed as explicit float4 re-loads (~70 float4/thread from L1/L2), W padded
// (zero when j<i) AND transposed (Wt[q][i]) so consecutive i -> merged s_load.
// Live set ~40 VGPR -> no sinking, high occupancy.

typedef float f2 __attribute__((ext_vector_type(2)));

#define C0 32
#define C1 16
#define NODE_F 80
#define NG_CONST 1024
#define NPB 320                 // 1 node/thread; phase2: 16 groups x 20 float4-cols

#define SELU_SCALE 1.0507009873554804934193349852946
#define SELU_ALPHA 1.6732632423543772848170429916717
#define LOG2E      1.4426950408889634073599246810019
#define SQRT3      1.7320508075688772935274463415059

#define CS2 ((float)LOG2E)             // si scale, scalar part
#define CV2 ((float)(LOG2E / SQRT3))   // vi scale, vector part

// ws float layout:
//   [0, 81920)       S accum [1024][80]
//   [81920, 82944)   z accum [1024]
//   [82944, 83968)   Wst: transposed padded scalar W, f2[q=16][i=32]
//   [83968, 84224)   Wvt: transposed padded vector W, f2[q=8][i=16]
#define WS_S   0
#define WS_Z   81920
#define WS_WST 82944
#define WS_WVT 83968

__device__ __forceinline__ int ks_idx(int i, int j) { return i * C0 - (i * (i - 1)) / 2 + (j - i); }
__device__ __forceinline__ int kv_idx(int i, int j) { return 528 + i * C1 - (i * (i - 1)) / 2 + (j - i); }

__global__ __launch_bounds__(256) void prep_kernel(
    const float* __restrict__ W, float* __restrict__ ws)
{
    const int t = blockIdx.x * blockDim.x + threadIdx.x;
    if (t < 82944) {
        ws[t] = 0.0f;                           // S and z accumulators
    } else if (t < 82944 + 512) {               // Wst[q][i], q<16, i<32
        int u = t - 82944;
        int q = u >> 5, i = u & 31;
        int j0 = 2 * q, j1 = 2 * q + 1;
        ws[WS_WST + 2 * u]     = (j0 >= i) ? W[ks_idx(i, j0)] : 0.0f;
        ws[WS_WST + 2 * u + 1] = (j1 >= i) ? W[ks_idx(i, j1)] : 0.0f;
    } else if (t < 82944 + 512 + 128) {         // Wvt[q][i], q<8, i<16
        int u = t - 82944 - 512;
        int q = u >> 4, i = u & 15;
        int j0 = 2 * q, j1 = 2 * q + 1;
        ws[WS_WVT + 2 * u]     = (j0 >= i) ? W[kv_idx(i, j0)] : 0.0f;
        ws[WS_WVT + 2 * u + 1] = (j1 >= i) ? W[kv_idx(i, j1)] : 0.0f;
    }
}

__global__ __launch_bounds__(NPB) void main_kernel(
    const float* __restrict__ nf, const int* __restrict__ bi,
    const float* __restrict__ ws, float* __restrict__ S,
    float* __restrict__ z, int N)
{
    __shared__ float exl[NPB];
    __shared__ int   bil[NPB];

    const int tid  = threadIdx.x;
    const int base = blockIdx.x * NPB;
    const float4* g4 = (const float4*)nf;
    const f2* Wst = (const f2*)(ws + WS_WST);
    const f2* Wvt = (const f2*)(ws + WS_WVT);

    const int  n     = base + tid;
    const bool valid = (n < N);
    const int  nn    = valid ? n : (N - 1);
    bil[tid] = bi[nn];

    const float4* rp = g4 + (size_t)nn * 20;    // this thread's row, float4 view

    f2 accA[2], accB[2];
    accA[0] = (f2)0.f; accA[1] = (f2)0.f; accB[0] = (f2)0.f; accB[1] = (f2)0.f;

    // ---------- scalar part: i-blocks of 8 channels, j-pairs streamed ----------
    #pragma unroll
    for (int ib = 0; ib < 4; ++ib) {
        float4 a0 = rp[2 * ib], a1 = rp[2 * ib + 1];
        float su[8];                            // live i-block, scaled by log2e
        su[0] = a0.x * CS2; su[1] = a0.y * CS2; su[2] = a0.z * CS2; su[3] = a0.w * CS2;
        su[4] = a1.x * CS2; su[5] = a1.y * CS2; su[6] = a1.z * CS2; su[7] = a1.w * CS2;

        #pragma unroll
        for (int qq = 4 * ib; qq < 16; qq += 2) {   // two j-pairs per float4 re-load
            float4 v = rp[qq >> 1];                 // s[2qq .. 2qq+3]
            f2 sj0 = f2{v.x, v.y};
            f2 sj1 = f2{v.z, v.w};
            #pragma unroll
            for (int u = 0; u < 8; ++u) {
                const int i = 8 * ib + u;
                {   // q = qq
                    f2 f = sj0 * (f2)su[u];
                    f2 p = __builtin_elementwise_max(f, (f2)0.f);
                    f2 m = __builtin_elementwise_min(f, (f2)0.f);
                    f2 e; e.x = __builtin_amdgcn_exp2f(m.x);
                          e.y = __builtin_amdgcn_exp2f(m.y);
                    f2 w = Wst[qq * 32 + i];        // padded: 0 when j<i
                    accA[0] = __builtin_elementwise_fma(w, p, accA[0]);
                    accB[0] = __builtin_elementwise_fma(w, e, accB[0]);
                }
                {   // q = qq+1
                    f2 f = sj1 * (f2)su[u];
                    f2 p = __builtin_elementwise_max(f, (f2)0.f);
                    f2 m = __builtin_elementwise_min(f, (f2)0.f);
                    f2 e; e.x = __builtin_amdgcn_exp2f(m.x);
                          e.y = __builtin_amdgcn_exp2f(m.y);
                    f2 w = Wst[(qq + 1) * 32 + i];
                    accA[1] = __builtin_elementwise_fma(w, p, accA[1]);
                    accB[1] = __builtin_elementwise_fma(w, e, accB[1]);
                }
            }
        }
    }

    // ---------- vector part: i-blocks of 4 vectors, j-vector-groups streamed ----------
    #pragma unroll
    for (int ib = 0; ib < 4; ++ib) {
        float4 b0 = rp[8 + 3 * ib], b1 = rp[9 + 3 * ib], b2 = rp[10 + 3 * ib];
        float vi[4][3];                         // live i-block, scaled by log2e/sqrt3
        vi[0][0] = b0.x * CV2; vi[0][1] = b0.y * CV2; vi[0][2] = b0.z * CV2;
        vi[1][0] = b0.w * CV2; vi[1][1] = b1.x * CV2; vi[1][2] = b1.y * CV2;
        vi[2][0] = b1.z * CV2; vi[2][1] = b1.w * CV2; vi[2][2] = b2.x * CV2;
        vi[3][0] = b2.y * CV2; vi[3][1] = b2.z * CV2; vi[3][2] = b2.w * CV2;

        #pragma unroll
        for (int qq = 2 * ib; qq < 8; qq += 2) {    // 4 j-vectors per 3 float4 re-loads
            const int jb = 8 + 3 * (qq >> 1);       // FIXED: floats 32+6qq => float4 8+3*(qq/2)
            float4 A = rp[jb], B = rp[jb + 1], C = rp[jb + 2];
            // j-vectors: a=2qq, b=2qq+1, c=2qq+2, d=2qq+3
            const float ax = A.x, ay = A.y, az = A.z;
            const float bx = A.w, by = B.x, bz = B.y;
            const float cx = B.z, cy = B.w, cz = C.x;
            const float dx = C.y, dy = C.z, dz = C.w;
            #pragma unroll
            for (int u = 0; u < 4; ++u) {
                const int i = 4 * ib + u;
                const float x = vi[u][0], y = vi[u][1], zc = vi[u][2];
                {   // q = qq: pair (a, b)
                    f2 f = f2{fmaf(x, ax, fmaf(y, ay, zc * az)),
                              fmaf(x, bx, fmaf(y, by, zc * bz))};
                    f2 p = __builtin_elementwise_max(f, (f2)0.f);
                    f2 m = __builtin_elementwise_min(f, (f2)0.f);
                    f2 e; e.x = __builtin_amdgcn_exp2f(m.x);
                          e.y = __builtin_amdgcn_exp2f(m.y);
                    f2 w = Wvt[qq * 16 + i];
                    accA[0] = __builtin_elementwise_fma(w, p, accA[0]);
                    accB[0] = __builtin_elementwise_fma(w, e, accB[0]);
                }
                {   // q = qq+1: pair (c, d)
                    f2 f = f2{fmaf(x, cx, fmaf(y, cy, zc * cz)),
                              fmaf(x, dx, fmaf(y, dy, zc * dz))};
                    f2 p = __builtin_elementwise_max(f, (f2)0.f);
                    f2 m = __builtin_elementwise_min(f, (f2)0.f);
                    f2 e; e.x = __builtin_amdgcn_exp2f(m.x);
                          e.y = __builtin_amdgcn_exp2f(m.y);
                    f2 w = Wvt[(qq + 1) * 16 + i];
                    accA[1] = __builtin_elementwise_fma(w, p, accA[1]);
                    accB[1] = __builtin_elementwise_fma(w, e, accB[1]);
                }
            }
        }
    }

    const float A1 = accA[0].x + accA[0].y + accA[1].x + accA[1].y;
    const float A2 = accB[0].x + accB[0].y + accB[1].x + accB[1].y;
    const float l2 = fmaf((float)SELU_SCALE, A1,
                          (float)(SELU_SCALE * SELU_ALPHA * LOG2E) * A2);
    exl[tid] = valid ? __builtin_amdgcn_exp2f(l2) : 0.0f;
    __syncthreads();

    // ---- phase 2 (validated r5): thread (no, c4) sums 20 contiguous nodes, flush per run ----
    const int no = tid / 20;       // 0..15
    const int c4 = tid % 20;
    int cg = bil[no * 20];
    float4 acc = make_float4(0.f, 0.f, 0.f, 0.f);
    float  zacc = 0.0f;

    #pragma unroll
    for (int k = 0; k < 20; ++k) {
        const int nl = no * 20 + k;
        const int g2 = bil[nl];
        if (g2 != cg) {
            unsafeAtomicAdd(&S[cg * NODE_F + c4 * 4 + 0], acc.x);
            unsafeAtomicAdd(&S[cg * NODE_F + c4 * 4 + 1], acc.y);
            unsafeAtomicAdd(&S[cg * NODE_F + c4 * 4 + 2], acc.z);
            unsafeAtomicAdd(&S[cg * NODE_F + c4 * 4 + 3], acc.w);
            if (c4 == 0) unsafeAtomicAdd(&z[cg], zacc);
            acc = make_float4(0.f, 0.f, 0.f, 0.f); zacc = 0.0f; cg = g2;
        }
        int idx = base + nl; if (idx > N - 1) idx = N - 1;   // pad nodes have w=0
        const float  w = exl[nl];
        const float4 v = g4[(size_t)idx * 20 + c4];
        acc.x = fmaf(v.x, w, acc.x); acc.y = fmaf(v.y, w, acc.y);
        acc.z = fmaf(v.z, w, acc.z); acc.w = fmaf(v.w, w, acc.w);
        zacc += w;
    }
    unsafeAtomicAdd(&S[cg * NODE_F + c4 * 4 + 0], acc.x);
    unsafeAtomicAdd(&S[cg * NODE_F + c4 * 4 + 1], acc.y);
    unsafeAtomicAdd(&S[cg * NODE_F + c4 * 4 + 2], acc.z);
    unsafeAtomicAdd(&S[cg * NODE_F + c4 * 4 + 3], acc.w);
    if (c4 == 0) unsafeAtomicAdd(&z[cg], zacc);
}

__global__ __launch_bounds__(256) void divide_kernel(
    const float* __restrict__ S, const float* __restrict__ z,
    float* __restrict__ out)
{
    const int t = blockIdx.x * blockDim.x + threadIdx.x;
    if (t >= NG_CONST * NODE_F) return;
    const float zz = z[t / NODE_F];
    out[t] = (zz > 0.0f) ? (S[t] / zz) : 0.0f;
}

extern "C" void kernel_launch(void* const* d_in, const int* in_sizes, int n_in,
                              void* d_out, int out_size, void* d_ws, size_t ws_size,
                              hipStream_t stream) {
    const float* nf = (const float*)d_in[0];   // (N, 80) f32
    const int*   bi = (const int*)d_in[1];     // (N,) i32 sorted
    // d_in[2] = num_graphs (static 1024)
    const float* W  = (const float*)d_in[3];   // (664,) f32
    float* out = (float*)d_out;

    const int N = in_sizes[0] / NODE_F;
    float* ws = (float*)d_ws;
    float* S  = ws + WS_S;
    float* z  = ws + WS_Z;

    hipLaunchKernelGGL(prep_kernel, dim3(330), dim3(256), 0, stream, W, ws);
    hipLaunchKernelGGL(main_kernel, dim3((N + NPB - 1) / NPB), dim3(NPB),
                       0, stream, nf, bi, ws, S, z, N);
    hipLaunchKernelGGL(divide_kernel, dim3((NG_CONST * NODE_F + 255) / 256), dim3(256),
                       0, stream, S, z, out);
}